// Round 2
// baseline (181.957 us; speedup 1.0000x reference)
//
#include <hip/hip_runtime.h>

#define B_ 4
#define C_ 256
#define N_ 4096
#define E_ 32

typedef _Float16 f16x8 __attribute__((ext_vector_type(8)));
typedef float f32x4 __attribute__((ext_vector_type(4)));

// ---------------------------------------------------------------------------
// Kernel 1: fused K/Q/V 1x1-conv projections via f16 MFMA.
//   f = Wk x + bk -> Kb[b][n][e]   (key,   [N,E] f16)
//   g = Wq x + bq -> Qb[b][n][e]   (query, [N,E] f16)
//   h = Wv x + bv -> Vb[b][e][n]   (value, [E,N] f16)
// Block: (b, 64-wide n tile), 256 threads = 4 waves, wave owns 16 n.
// ---------------------------------------------------------------------------
__global__ __launch_bounds__(256) void proj_kernel(
    const float* __restrict__ x,
    const float* __restrict__ Wk, const float* __restrict__ bk,
    const float* __restrict__ Wq, const float* __restrict__ bq,
    const float* __restrict__ Wv, const float* __restrict__ bv,
    _Float16* __restrict__ Qb, _Float16* __restrict__ Kb, _Float16* __restrict__ Vb)
{
    const int b  = blockIdx.x >> 6;
    const int n0 = (blockIdx.x & 63) << 6;
    const int t    = threadIdx.x;
    const int lane = t & 63;
    const int wave = t >> 6;
    const int l15  = lane & 15;
    const int quad = lane >> 4;

    // pad rows to 264 f16 (528 B): 16B-aligned b128 reads, 2-way banks (free)
    __shared__ _Float16 xT[64][264];      // x tile transposed: [n_local][c]
    __shared__ _Float16 Wl[3][32][264];   // weights as f16: [mat][e][c]

    {
        const float* Ws[3] = {Wk, Wq, Wv};
        for (int m = 0; m < 3; ++m)
            for (int idx = t; idx < E_ * C_; idx += 256)
                Wl[m][idx >> 8][idx & 255] = (_Float16)Ws[m][idx];
    }
    // FIXED (R1): full coverage of the 64x256 tile (was it*1024+t, 1/4 cover
    // -> stale LDS garbage -> NaN). flat&63 = n_local (coalesced), flat>>6 = c.
    for (int flat = t; flat < 64 * 256; flat += 256) {
        int c = flat >> 6, j = flat & 63;
        xT[j][c] = (_Float16)x[(size_t)(b * C_ + c) * N_ + n0 + j];
    }
    __syncthreads();

    // B-frags: B[k=c][n=l15] -> xT[n][c], 8 k-chunks of 32
    f16x8 Bf[8];
    for (int kk = 0; kk < 8; ++kk)
        Bf[kk] = *(const f16x8*)&xT[wave * 16 + l15][kk * 32 + quad * 8];

    const float* biases[3] = {bk, bq, bv};
    for (int m = 0; m < 3; ++m) {
      for (int et = 0; et < 2; ++et) {
        f32x4 acc = {0.f, 0.f, 0.f, 0.f};
        for (int kk = 0; kk < 8; ++kk) {
            // A[m=e][k=c] from Wl
            f16x8 Af = *(const f16x8*)&Wl[m][et * 16 + l15][kk * 32 + quad * 8];
            acc = __builtin_amdgcn_mfma_f32_16x16x32_f16(Af, Bf[kk], acc, 0, 0, 0);
        }
        // C/D layout: col(n)=lane&15, row(e)=quad*4+r
        const int n = n0 + wave * 16 + l15;
        for (int r = 0; r < 4; ++r) {
            const int e = et * 16 + quad * 4 + r;
            float v = acc[r] + biases[m][e];
            _Float16 hv = (_Float16)v;
            if      (m == 0) Kb[(size_t)(b * N_ + n) * E_ + e] = hv;
            else if (m == 1) Qb[(size_t)(b * N_ + n) * E_ + e] = hv;
            else             Vb[(size_t)(b * E_ + e) * N_ + n] = hv;
        }
      }
    }
}

// ---------------------------------------------------------------------------
// Kernel 2: flash attention (row softmax over keys i for each query j).
//   O[j][e] = sum_i softmax_i(Q[j]·K[i]) * V[i][e], stored /l as f16 [N,E].
// Block: (b, 64 query rows), 4 independent waves x 16 rows. i-tile = 64.
// ---------------------------------------------------------------------------
__global__ __launch_bounds__(256) void attn_kernel(
    const _Float16* __restrict__ Qb, const _Float16* __restrict__ Kb,
    const _Float16* __restrict__ Vb, _Float16* __restrict__ Ob)
{
    const int b    = blockIdx.x >> 6;
    const int wave = threadIdx.x >> 6;
    const int lane = threadIdx.x & 63;
    const int l15  = lane & 15, quad = lane >> 4;
    const int j0   = ((blockIdx.x & 63) << 6) + (wave << 4);

    // per-wave P transpose buffer; rows padded to 72 f16 (144 B, 16B-aligned)
    __shared__ _Float16 pb[4][16][72];

    // Q A-frag: A[m=j][k=e], lane -> row j0+l15, k = quad*8..quad*8+7
    f16x8 Qf = *(const f16x8*)(Qb + (size_t)(b * N_ + j0 + l15) * E_ + quad * 8);

    f32x4 O0 = {0, 0, 0, 0}, O1 = {0, 0, 0, 0};
    float mrow[4], lrow[4];
    for (int r = 0; r < 4; ++r) { mrow[r] = -__builtin_inff(); lrow[r] = 0.f; }

    const _Float16* Kbase = Kb + (size_t)b * N_ * E_;
    const _Float16* Vbase = Vb + (size_t)b * E_ * N_;

    for (int i0 = 0; i0 < N_; i0 += 64) {
        // S[j][i]: 4 tiles of 16 keys, one MFMA each (K-dim = E = 32)
        f32x4 S[4];
        for (int tile = 0; tile < 4; ++tile) {
            f16x8 Kf = *(const f16x8*)(Kbase + (size_t)(i0 + tile * 16 + l15) * E_ + quad * 8);
            f32x4 z = {0, 0, 0, 0};
            S[tile] = __builtin_amdgcn_mfma_f32_16x16x32_f16(Qf, Kf, z, 0, 0, 0);
        }
        // online softmax; C layout: row j = quad*4+r (16 lanes share a row set)
        for (int r = 0; r < 4; ++r) {
            float mx = fmaxf(fmaxf(S[0][r], S[1][r]), fmaxf(S[2][r], S[3][r]));
            mx = fmaxf(mx, __shfl_xor(mx, 1, 16));
            mx = fmaxf(mx, __shfl_xor(mx, 2, 16));
            mx = fmaxf(mx, __shfl_xor(mx, 4, 16));
            mx = fmaxf(mx, __shfl_xor(mx, 8, 16));
            float mnew  = fmaxf(mrow[r], mx);
            float alpha = __expf(mrow[r] - mnew);
            mrow[r] = mnew;
            float psum = 0.f;
            for (int tile = 0; tile < 4; ++tile) {
                float p = __expf(S[tile][r] - mnew);
                S[tile][r] = p;
                psum += p;
            }
            psum += __shfl_xor(psum, 1, 16);
            psum += __shfl_xor(psum, 2, 16);
            psum += __shfl_xor(psum, 4, 16);
            psum += __shfl_xor(psum, 8, 16);
            lrow[r] = lrow[r] * alpha + psum;
            O0[r] *= alpha;
            O1[r] *= alpha;
        }
        // P (C layout) -> A-frag layout via per-wave LDS round-trip
        for (int r = 0; r < 4; ++r)
            for (int tile = 0; tile < 4; ++tile)
                pb[wave][quad * 4 + r][tile * 16 + l15] = (_Float16)S[tile][r];
        asm volatile("s_waitcnt lgkmcnt(0)" ::: "memory");
        f16x8 P0 = *(const f16x8*)&pb[wave][l15][quad * 8];        // k = i 0..31
        f16x8 P1 = *(const f16x8*)&pb[wave][l15][32 + quad * 8];   // k = i 32..63
        // V B-frags: B[k=i][n=e] from Vb[e][i] (contiguous in i)
        f16x8 V0a = *(const f16x8*)(Vbase + (size_t)l15 * N_        + i0 +      quad * 8);
        f16x8 V0b = *(const f16x8*)(Vbase + (size_t)l15 * N_        + i0 + 32 + quad * 8);
        f16x8 V1a = *(const f16x8*)(Vbase + (size_t)(16 + l15) * N_ + i0 +      quad * 8);
        f16x8 V1b = *(const f16x8*)(Vbase + (size_t)(16 + l15) * N_ + i0 + 32 + quad * 8);
        O0 = __builtin_amdgcn_mfma_f32_16x16x32_f16(P0, V0a, O0, 0, 0, 0);
        O0 = __builtin_amdgcn_mfma_f32_16x16x32_f16(P1, V0b, O0, 0, 0, 0);
        O1 = __builtin_amdgcn_mfma_f32_16x16x32_f16(P0, V1a, O1, 0, 0, 0);
        O1 = __builtin_amdgcn_mfma_f32_16x16x32_f16(P1, V1b, O1, 0, 0, 0);
    }

    // epilogue: divide by l, store f16 [b][j][e]
    for (int r = 0; r < 4; ++r) {
        float inv = 1.0f / lrow[r];
        size_t base = (size_t)(b * N_ + j0 + quad * 4 + r) * E_;
        Ob[base + l15]      = (_Float16)(O0[r] * inv);
        Ob[base + 16 + l15] = (_Float16)(O1[r] * inv);
    }
}

// ---------------------------------------------------------------------------
// Kernel 3: output projection + bias + residual. o[c][n] = Wo[c]·v[n] + bo[c];
// y = 0.5*o + x. Also writes gamma. MFMA: A=Wo(f16, LDS), B=Ob rows.
// ---------------------------------------------------------------------------
__global__ __launch_bounds__(256) void out_kernel(
    const _Float16* __restrict__ Ob, const float* __restrict__ Wo,
    const float* __restrict__ bo, const float* __restrict__ x,
    float* __restrict__ out)
{
    const int b  = blockIdx.x >> 6;
    const int n0 = (blockIdx.x & 63) << 6;
    const int t = threadIdx.x, lane = t & 63, wave = t >> 6;
    const int l15 = lane & 15, quad = lane >> 4;

    __shared__ _Float16 Wl[256][40];   // [c][e], padded rows (80 B)
    for (int idx = t; idx < C_ * E_; idx += 256)
        Wl[idx >> 5][idx & 31] = (_Float16)Wo[idx];
    __syncthreads();

    const int nloc = wave * 16 + l15;
    const int n = n0 + nloc;
    // B[k=e][n] from Ob[n][e] (contiguous in e)
    f16x8 Bf = *(const f16x8*)(Ob + (size_t)(b * N_ + n) * E_ + quad * 8);

    float* out_y = out;
    float* out_o = out + (size_t)B_ * C_ * N_;

    for (int ct = 0; ct < 16; ++ct) {
        f16x8 Af = *(const f16x8*)&Wl[ct * 16 + l15][quad * 8];  // A[m=c][k=e]
        f32x4 z = {0, 0, 0, 0};
        f32x4 acc = __builtin_amdgcn_mfma_f32_16x16x32_f16(Af, Bf, z, 0, 0, 0);
        for (int r = 0; r < 4; ++r) {
            const int c = ct * 16 + quad * 4 + r;
            size_t idx = (size_t)(b * C_ + c) * N_ + n0 + nloc;
            float ov = acc[r] + bo[c];
            out_o[idx] = ov;
            out_y[idx] = 0.5f * ov + x[idx];
        }
    }
    if (blockIdx.x == 0 && t == 0)
        out[(size_t)2 * B_ * C_ * N_] = 0.5f;   // gamma (non-learned) = 0.5
}

// ---------------------------------------------------------------------------
extern "C" void kernel_launch(void* const* d_in, const int* in_sizes, int n_in,
                              void* d_out, int out_size, void* d_ws, size_t ws_size,
                              hipStream_t stream)
{
    const float* x  = (const float*)d_in[0];
    const float* Wk = (const float*)d_in[1];
    const float* bk = (const float*)d_in[2];
    const float* Wq = (const float*)d_in[3];
    const float* bq = (const float*)d_in[4];
    const float* Wv = (const float*)d_in[5];
    const float* bv = (const float*)d_in[6];
    const float* Wo = (const float*)d_in[7];
    const float* bo = (const float*)d_in[8];
    float* out = (float*)d_out;

    char* ws = (char*)d_ws;
    _Float16* Qb = (_Float16*)(ws);                        // 1 MB  [B][N][E]
    _Float16* Kb = (_Float16*)(ws + (1u << 20));           // 1 MB  [B][N][E]
    _Float16* Vb = (_Float16*)(ws + (2u << 20));           // 1 MB  [B][E][N]
    _Float16* Ob = (_Float16*)(ws + (3u << 20));           // 1 MB  [B][N][E]

    dim3 grid(B_ * (N_ / 64)), blk(256);
    proj_kernel<<<grid, blk, 0, stream>>>(x, Wk, bk, Wq, bq, Wv, bv, Qb, Kb, Vb);
    attn_kernel<<<grid, blk, 0, stream>>>(Qb, Kb, Vb, Ob);
    out_kernel<<<grid, blk, 0, stream>>>(Ob, Wo, bo, x, out);
}

// Round 3
// 156.175 us; speedup vs baseline: 1.1651x; 1.1651x over previous
//
#include <hip/hip_runtime.h>

#define B_ 4
#define C_ 256
#define N_ 4096
#define E_ 32

typedef _Float16 f16x8 __attribute__((ext_vector_type(8)));
typedef _Float16 f16x4 __attribute__((ext_vector_type(4)));
typedef float f32x4 __attribute__((ext_vector_type(4)));

#define LOG2E 1.44269504088896f

// ---------------------------------------------------------------------------
// Kernel 1: fused K/Q/V 1x1-conv projections via f16 MFMA.
//   Kb[b][n][e] = f, Qb[b][n][e] = g * log2(e)  (log2-domain softmax),
//   Vb[b][e][n] = h.
// ---------------------------------------------------------------------------
__global__ __launch_bounds__(256) void proj_kernel(
    const float* __restrict__ x,
    const float* __restrict__ Wk, const float* __restrict__ bk,
    const float* __restrict__ Wq, const float* __restrict__ bq,
    const float* __restrict__ Wv, const float* __restrict__ bv,
    _Float16* __restrict__ Qb, _Float16* __restrict__ Kb, _Float16* __restrict__ Vb)
{
    const int b  = blockIdx.x >> 6;
    const int n0 = (blockIdx.x & 63) << 6;
    const int t    = threadIdx.x;
    const int lane = t & 63;
    const int wave = t >> 6;
    const int l15  = lane & 15;
    const int quad = lane >> 4;

    __shared__ _Float16 xT[64][264];      // x tile transposed: [n_local][c]
    __shared__ _Float16 Wl[3][32][264];   // weights as f16: [mat][e][c]

    {   // weights: float4 loads, f16x4 LDS stores (24 iters/thread)
        const float* Ws[3] = {Wk, Wq, Wv};
        for (int m = 0; m < 3; ++m)
            for (int i4 = t; i4 < (E_ * C_) / 4; i4 += 256) {
                float4 wv = ((const float4*)Ws[m])[i4];
                int e = (i4 * 4) >> 8, c = (i4 * 4) & 255;
                _Float16 tmp[4] = {(_Float16)wv.x, (_Float16)wv.y,
                                   (_Float16)wv.z, (_Float16)wv.w};
                *(f16x4*)&Wl[m][e][c] = *(f16x4*)tmp;
            }
    }
    // x tile: float4 along n (coalesced 256B/16 lanes), scalar transposed stores
    for (int i4 = t; i4 < (64 * 256) / 4; i4 += 256) {
        int j4 = (i4 & 15) * 4;
        int c  = i4 >> 4;
        float4 xv = *(const float4*)(x + (size_t)(b * C_ + c) * N_ + n0 + j4);
        xT[j4 + 0][c] = (_Float16)xv.x;
        xT[j4 + 1][c] = (_Float16)xv.y;
        xT[j4 + 2][c] = (_Float16)xv.z;
        xT[j4 + 3][c] = (_Float16)xv.w;
    }
    __syncthreads();

    f16x8 Bf[8];
    for (int kk = 0; kk < 8; ++kk)
        Bf[kk] = *(const f16x8*)&xT[wave * 16 + l15][kk * 32 + quad * 8];

    const float* biases[3] = {bk, bq, bv};
    for (int m = 0; m < 3; ++m) {
      const float sc = (m == 1) ? LOG2E : 1.0f;   // fold log2e into q
      for (int et = 0; et < 2; ++et) {
        f32x4 acc = {0.f, 0.f, 0.f, 0.f};
        for (int kk = 0; kk < 8; ++kk) {
            f16x8 Af = *(const f16x8*)&Wl[m][et * 16 + l15][kk * 32 + quad * 8];
            acc = __builtin_amdgcn_mfma_f32_16x16x32_f16(Af, Bf[kk], acc, 0, 0, 0);
        }
        const int n = n0 + wave * 16 + l15;
        for (int r = 0; r < 4; ++r) {
            const int e = et * 16 + quad * 4 + r;
            float v = (acc[r] + biases[m][e]) * sc;
            _Float16 hv = (_Float16)v;
            if      (m == 0) Kb[(size_t)(b * N_ + n) * E_ + e] = hv;
            else if (m == 1) Qb[(size_t)(b * N_ + n) * E_ + e] = hv;
            else             Vb[(size_t)(b * E_ + e) * N_ + n] = hv;
        }
      }
    }
}

// ---------------------------------------------------------------------------
// Kernel 2: split-i flash attention. Block = 1 j-group (16 query rows),
// 4 waves = 4 i-splits of 1024 keys each. i-tile = 128 (8 S-MFMAs).
// Online max only (wave-uniform per row); l kept per-lane, reduced at end.
// Writes partial O (f16) + (m,l) per row to ws; merge_kernel combines.
// ---------------------------------------------------------------------------
__global__ __launch_bounds__(256, 4) void attn_kernel(
    const _Float16* __restrict__ Qb, const _Float16* __restrict__ Kb,
    const _Float16* __restrict__ Vb,
    _Float16* __restrict__ Opart, float* __restrict__ MLpart)
{
    const int wave = threadIdx.x >> 6;     // = split 0..3
    const int lane = threadIdx.x & 63;
    const int l15  = lane & 15, quad = lane >> 4;
    const int jg   = blockIdx.x;           // 0..1023
    const int b    = jg >> 8;
    const int j0   = (jg & 255) << 4;

    __shared__ _Float16 pb[4][16][136];    // per-wave P transpose, 128+8 pad

    f16x8 Qf = *(const f16x8*)(Qb + (size_t)(b * N_ + j0 + l15) * E_ + quad * 8);

    f32x4 O0 = {0, 0, 0, 0}, O1 = {0, 0, 0, 0};
    float mrow[4], lsum[4];
    for (int r = 0; r < 4; ++r) { mrow[r] = -1e30f; lsum[r] = 0.f; }

    const _Float16* Kbase = Kb + (size_t)b * N_ * E_;
    const _Float16* Vbase = Vb + (size_t)b * E_ * N_;
    const int ibase = wave << 10;          // split * 1024

    for (int it = 0; it < 8; ++it) {
        const int i0 = ibase + it * 128;
        f32x4 S[8];
        for (int s = 0; s < 8; ++s) {
            f16x8 Kf = *(const f16x8*)(Kbase + (size_t)(i0 + s * 16 + l15) * E_ + quad * 8);
            f32x4 z = {0, 0, 0, 0};
            S[s] = __builtin_amdgcn_mfma_f32_16x16x32_f16(Qf, Kf, z, 0, 0, 0);
        }
        for (int r = 0; r < 4; ++r) {
            float mx = fmaxf(fmaxf(fmaxf(S[0][r], S[1][r]), fmaxf(S[2][r], S[3][r])),
                             fmaxf(fmaxf(S[4][r], S[5][r]), fmaxf(S[6][r], S[7][r])));
            mx = fmaxf(mx, __shfl_xor(mx, 1, 16));
            mx = fmaxf(mx, __shfl_xor(mx, 2, 16));
            mx = fmaxf(mx, __shfl_xor(mx, 4, 16));
            mx = fmaxf(mx, __shfl_xor(mx, 8, 16));
            float mnew  = fmaxf(mrow[r], mx);
            float alpha = exp2f(mrow[r] - mnew);     // log2 domain
            mrow[r] = mnew;
            float ps = 0.f;
            for (int s = 0; s < 8; ++s) {
                float p = exp2f(S[s][r] - mnew);
                S[s][r] = p;
                ps += p;
            }
            lsum[r] = lsum[r] * alpha + ps;          // per-lane partial l
            O0[r] *= alpha;
            O1[r] *= alpha;
            for (int s = 0; s < 8; ++s)
                pb[wave][quad * 4 + r][s * 16 + l15] = (_Float16)S[s][r];
        }
        asm volatile("s_waitcnt lgkmcnt(0)" ::: "memory");
        for (int c = 0; c < 4; ++c) {
            f16x8 Pc = *(const f16x8*)&pb[wave][l15][c * 32 + quad * 8];
            f16x8 Va = *(const f16x8*)(Vbase + (size_t)l15 * N_ + i0 + c * 32 + quad * 8);
            f16x8 Vc = *(const f16x8*)(Vbase + (size_t)(16 + l15) * N_ + i0 + c * 32 + quad * 8);
            O0 = __builtin_amdgcn_mfma_f32_16x16x32_f16(Pc, Va, O0, 0, 0, 0);
            O1 = __builtin_amdgcn_mfma_f32_16x16x32_f16(Pc, Vc, O1, 0, 0, 0);
        }
    }
    // deferred l reduction across the row's 16 lanes
    for (int r = 0; r < 4; ++r) {
        float l = lsum[r];
        l += __shfl_xor(l, 1, 16);
        l += __shfl_xor(l, 2, 16);
        l += __shfl_xor(l, 4, 16);
        l += __shfl_xor(l, 8, 16);
        lsum[r] = l;
    }
    const size_t pbase = ((size_t)jg * 4 + wave) * 16;
    for (int r = 0; r < 4; ++r) {
        size_t row = pbase + quad * 4 + r;
        Opart[row * 32 + l15]      = (_Float16)O0[r];
        Opart[row * 32 + 16 + l15] = (_Float16)O1[r];
        if (l15 == 0) {
            MLpart[row * 2]     = mrow[r];
            MLpart[row * 2 + 1] = lsum[r];
        }
    }
}

// ---------------------------------------------------------------------------
// Kernel 2b: merge the 4 i-splits (log-sum-exp combine), write Ob f16 [N,E].
// One thread per output row (16384 rows).
// ---------------------------------------------------------------------------
__global__ __launch_bounds__(256) void merge_kernel(
    const _Float16* __restrict__ Opart, const float* __restrict__ MLpart,
    _Float16* __restrict__ Ob)
{
    const int jrow = blockIdx.x * 256 + threadIdx.x;   // 0..16383
    const int jg = jrow >> 4, r = jrow & 15;

    float m[4], l[4], M = -1e30f;
    for (int s = 0; s < 4; ++s) {
        size_t row = ((size_t)jg * 4 + s) * 16 + r;
        m[s] = MLpart[row * 2];
        l[s] = MLpart[row * 2 + 1];
        M = fmaxf(M, m[s]);
    }
    float w[4], L = 0.f;
    for (int s = 0; s < 4; ++s) { w[s] = exp2f(m[s] - M); L += l[s] * w[s]; }
    const float inv = 1.f / L;

    float acc[32];
    for (int e = 0; e < 32; ++e) acc[e] = 0.f;
    for (int s = 0; s < 4; ++s) {
        size_t row = ((size_t)jg * 4 + s) * 16 + r;
        const f16x8* Op = (const f16x8*)(Opart + row * 32);
        for (int c = 0; c < 4; ++c) {
            f16x8 v = Op[c];
            for (int k = 0; k < 8; ++k) acc[c * 8 + k] += (float)v[k] * w[s];
        }
    }
    const int b = jg >> 8;
    const int n = ((jg & 255) << 4) + r;
    _Float16* dst = Ob + (size_t)(b * N_ + n) * E_;
    for (int c = 0; c < 4; ++c) {
        _Float16 tmp[8];
        for (int k = 0; k < 8; ++k) tmp[k] = (_Float16)(acc[c * 8 + k] * inv);
        ((f16x8*)dst)[c] = *(f16x8*)tmp;
    }
}

// ---------------------------------------------------------------------------
// Kernel 3: output projection + bias + residual, c-split for occupancy.
// Block = 64 n x 64 c (1024 blocks, 4/CU). y = 0.5*o + x; also writes o, gamma.
// ---------------------------------------------------------------------------
__global__ __launch_bounds__(256) void out_kernel(
    const _Float16* __restrict__ Ob, const float* __restrict__ Wo,
    const float* __restrict__ bo, const float* __restrict__ x,
    float* __restrict__ out)
{
    const int bi  = blockIdx.x;            // 0..1023
    const int b   = bi >> 8;
    const int rem = bi & 255;
    const int n0  = (rem >> 2) << 6;       // n tile of 64
    const int cq  = rem & 3;               // c quarter (64 channels)
    const int t = threadIdx.x, lane = t & 63, wave = t >> 6;
    const int l15 = lane & 15, quad = lane >> 4;

    __shared__ _Float16 Wl[64][40];        // [c_local][e], 80 B rows
    for (int i4 = t; i4 < (64 * E_) / 4; i4 += 256) {
        int c = (i4 * 4) >> 5, e = (i4 * 4) & 31;
        float4 wv = *(const float4*)(Wo + (size_t)(cq * 64 + c) * E_ + e);
        _Float16 tmp[4] = {(_Float16)wv.x, (_Float16)wv.y, (_Float16)wv.z, (_Float16)wv.w};
        *(f16x4*)&Wl[c][e] = *(f16x4*)tmp;
    }
    __syncthreads();

    const int nloc = wave * 16 + l15;
    f16x8 Bf = *(const f16x8*)(Ob + (size_t)(b * N_ + n0 + nloc) * E_ + quad * 8);

    float* out_y = out;
    float* out_o = out + (size_t)B_ * C_ * N_;

    for (int tt = 0; tt < 4; ++tt) {
        f16x8 Af = *(const f16x8*)&Wl[tt * 16 + l15][quad * 8];
        f32x4 z = {0, 0, 0, 0};
        f32x4 acc = __builtin_amdgcn_mfma_f32_16x16x32_f16(Af, Bf, z, 0, 0, 0);
        for (int r = 0; r < 4; ++r) {
            const int c = cq * 64 + tt * 16 + quad * 4 + r;
            size_t idx = (size_t)(b * C_ + c) * N_ + n0 + nloc;
            float ov = acc[r] + bo[c];
            out_o[idx] = ov;
            out_y[idx] = 0.5f * ov + x[idx];
        }
    }
    if (bi == 0 && t == 0)
        out[(size_t)2 * B_ * C_ * N_] = 0.5f;   // gamma (non-learned)
}

// ---------------------------------------------------------------------------
extern "C" void kernel_launch(void* const* d_in, const int* in_sizes, int n_in,
                              void* d_out, int out_size, void* d_ws, size_t ws_size,
                              hipStream_t stream)
{
    const float* x  = (const float*)d_in[0];
    const float* Wk = (const float*)d_in[1];
    const float* bk = (const float*)d_in[2];
    const float* Wq = (const float*)d_in[3];
    const float* bq = (const float*)d_in[4];
    const float* Wv = (const float*)d_in[5];
    const float* bv = (const float*)d_in[6];
    const float* Wo = (const float*)d_in[7];
    const float* bo = (const float*)d_in[8];
    float* out = (float*)d_out;

    char* ws = (char*)d_ws;
    _Float16* Qb    = (_Float16*)(ws);                   // 1 MB   [B][N][E]
    _Float16* Kb    = (_Float16*)(ws + (1u << 20));      // 1 MB   [B][N][E]
    _Float16* Vb    = (_Float16*)(ws + (2u << 20));      // 1 MB   [B][E][N]
    _Float16* Ob    = (_Float16*)(ws + (3u << 20));      // 1 MB   [B][N][E]
    _Float16* Opart = (_Float16*)(ws + (4u << 20));      // 4 MB   [65536][32] f16
    float*    MLpart= (float*)   (ws + (8u << 20));      // 512 KB [65536][2] f32

    proj_kernel <<<dim3(B_ * (N_ / 64)), dim3(256), 0, stream>>>(
        x, Wk, bk, Wq, bq, Wv, bv, Qb, Kb, Vb);
    attn_kernel <<<dim3(B_ * (N_ / 16)), dim3(256), 0, stream>>>(
        Qb, Kb, Vb, Opart, MLpart);
    merge_kernel<<<dim3(64), dim3(256), 0, stream>>>(Opart, MLpart, Ob);
    out_kernel  <<<dim3(4 * B_ * (N_ / 64)), dim3(256), 0, stream>>>(
        Ob, Wo, bo, x, out);
}

// Round 4
// 151.322 us; speedup vs baseline: 1.2024x; 1.0321x over previous
//
#include <hip/hip_runtime.h>

#define B_ 4
#define C_ 256
#define N_ 4096
#define E_ 32

typedef _Float16 f16x8 __attribute__((ext_vector_type(8)));
typedef _Float16 f16x4 __attribute__((ext_vector_type(4)));
typedef _Float16 f16x2 __attribute__((ext_vector_type(2)));
typedef float f32x4 __attribute__((ext_vector_type(4)));
typedef float f32x2 __attribute__((ext_vector_type(2)));

#define LOG2E 1.44269504088896f

// ---------------------------------------------------------------------------
// Kernel 1: K/Q/V 1x1-conv projections via f16 MFMA. One matrix per block
// (3x256 = 768 blocks, 3/CU) to fix the R3 1-block/CU serialization.
//   Kb[b][n][e] = f, Qb[b][n][e] = g * log2(e), Vb[b][e][n] = h.
// ---------------------------------------------------------------------------
__global__ __launch_bounds__(256) void proj_kernel(
    const float* __restrict__ x,
    const float* __restrict__ Wk, const float* __restrict__ bk,
    const float* __restrict__ Wq, const float* __restrict__ bq,
    const float* __restrict__ Wv, const float* __restrict__ bv,
    _Float16* __restrict__ Qb, _Float16* __restrict__ Kb, _Float16* __restrict__ Vb)
{
    const int m   = blockIdx.x >> 8;         // 0=K, 1=Q, 2=V
    const int rem = blockIdx.x & 255;
    const int b   = rem >> 6;
    const int n0  = (rem & 63) << 6;
    const int t    = threadIdx.x;
    const int lane = t & 63;
    const int wave = t >> 6;
    const int l15  = lane & 15;
    const int quad = lane >> 4;

    __shared__ _Float16 xT[64][264];   // x tile transposed: [n_local][c]
    __shared__ _Float16 Wl[32][264];   // this matrix's weights: [e][c]

    const float* W    = (m == 0) ? Wk : (m == 1) ? Wq : Wv;
    const float* bias = (m == 0) ? bk : (m == 1) ? bq : bv;

    for (int i4 = t; i4 < (E_ * C_) / 4; i4 += 256) {
        float4 wv = ((const float4*)W)[i4];
        int e = (i4 * 4) >> 8, c = (i4 * 4) & 255;
        f16x4 tp = {(_Float16)wv.x, (_Float16)wv.y, (_Float16)wv.z, (_Float16)wv.w};
        *(f16x4*)&Wl[e][c] = tp;
    }
    for (int i4 = t; i4 < (64 * 256) / 4; i4 += 256) {
        int j4 = (i4 & 15) * 4;
        int c  = i4 >> 4;
        float4 xv = *(const float4*)(x + (size_t)(b * C_ + c) * N_ + n0 + j4);
        xT[j4 + 0][c] = (_Float16)xv.x;
        xT[j4 + 1][c] = (_Float16)xv.y;
        xT[j4 + 2][c] = (_Float16)xv.z;
        xT[j4 + 3][c] = (_Float16)xv.w;
    }
    __syncthreads();

    f16x8 Bf[8];
    for (int kk = 0; kk < 8; ++kk)
        Bf[kk] = *(const f16x8*)&xT[wave * 16 + l15][kk * 32 + quad * 8];

    const float sc = (m == 1) ? LOG2E : 1.0f;
    for (int et = 0; et < 2; ++et) {
        f32x4 acc = {0.f, 0.f, 0.f, 0.f};
        for (int kk = 0; kk < 8; ++kk) {
            f16x8 Af = *(const f16x8*)&Wl[et * 16 + l15][kk * 32 + quad * 8];
            acc = __builtin_amdgcn_mfma_f32_16x16x32_f16(Af, Bf[kk], acc, 0, 0, 0);
        }
        const int n = n0 + wave * 16 + l15;
        for (int r = 0; r < 4; ++r) {
            const int e = et * 16 + quad * 4 + r;
            float v = (acc[r] + bias[e]) * sc;
            _Float16 hv = (_Float16)v;
            if      (m == 0) Kb[(size_t)(b * N_ + n) * E_ + e] = hv;
            else if (m == 1) Qb[(size_t)(b * N_ + n) * E_ + e] = hv;
            else             Vb[(size_t)(b * E_ + e) * N_ + n] = hv;
        }
    }
}

// ---------------------------------------------------------------------------
// Kernel 2: split-i flash attention with TRANSPOSED S (S^T = K x Q^T MFMA):
// lane = query j, i spread over regs+quads -> softmax max needs only 2 shfls,
// alpha/l are per-lane. PV: O^T = V x P (A=V from Vb[E][N], B=P). The 4 waves
// are the 4 i-splits; in-block LDS merge writes Ob directly (no merge kernel).
// ---------------------------------------------------------------------------
__global__ __launch_bounds__(256, 4) void attn_kernel(
    const _Float16* __restrict__ Qb, const _Float16* __restrict__ Kb,
    const _Float16* __restrict__ Vb, _Float16* __restrict__ Ob)
{
    const int wave = threadIdx.x >> 6;     // i-split 0..3
    const int lane = threadIdx.x & 63;
    const int l15  = lane & 15, quad = lane >> 4;
    const int jg   = blockIdx.x;           // 0..1023
    const int b    = jg >> 8;
    const int j0   = (jg & 255) << 4;

    __shared__ _Float16 pb[4][16][136];    // per-wave P^T->B-frag buffer
    __shared__ float    osum[4][16][36];   // per-wave scaled O^T for merge
    __shared__ float    mls[4][2][16];     // per-wave (m, l) per j

    // Q B-frag: B[k=e][n=j], lane j=l15, k=quad*8.. from Qb[j][e]
    f16x8 Qf = *(const f16x8*)(Qb + (size_t)(b * N_ + j0 + l15) * E_ + quad * 8);

    f32x4 O0 = {0, 0, 0, 0}, O1 = {0, 0, 0, 0};   // O^T[e][j], e 0..15 / 16..31
    float mrow = -1e30f, lsum = 0.f;               // per-lane (per-j) state

    const _Float16* Kbase = Kb + (size_t)b * N_ * E_;
    const _Float16* Vbase = Vb + (size_t)b * E_ * N_;
    const int ibase = wave << 10;

    for (int it = 0; it < 8; ++it) {
        const int i0 = ibase + it * 128;
        // S^T tiles: D[i][j], A=K (m=i), B=Q (n=j). i = tile*16 + quad*4 + r.
        f32x4 S[8];
        for (int s = 0; s < 8; ++s) {
            f16x8 Kf = *(const f16x8*)(Kbase + (size_t)(i0 + s * 16 + l15) * E_ + quad * 8);
            f32x4 z = {0, 0, 0, 0};
            S[s] = __builtin_amdgcn_mfma_f32_16x16x32_f16(Kf, Qf, z, 0, 0, 0);
        }
        // max over i: 32 in-lane regs + 2 shfls across quads
        float mx = -1e30f;
        for (int s = 0; s < 8; ++s)
            for (int r = 0; r < 4; ++r) mx = fmaxf(mx, S[s][r]);
        mx = fmaxf(mx, __shfl_xor(mx, 16));
        mx = fmaxf(mx, __shfl_xor(mx, 32));
        float mnew  = fmaxf(mrow, mx);
        float alpha = exp2f(mrow - mnew);          // log2 domain
        mrow = mnew;
        float ps = 0.f;
        for (int s = 0; s < 8; ++s)
            for (int r = 0; r < 4; ++r) {
                float p = exp2f(S[s][r] - mnew);
                S[s][r] = p;
                ps += p;
            }
        lsum = lsum * alpha + ps;
        for (int r = 0; r < 4; ++r) { O0[r] *= alpha; O1[r] *= alpha; }
        // P^T (D-layout) -> B-frag layout: packed b64 writes, b128 reads
        for (int s = 0; s < 8; ++s) {
            f16x4 tp = {(_Float16)S[s][0], (_Float16)S[s][1],
                        (_Float16)S[s][2], (_Float16)S[s][3]};
            *(f16x4*)&pb[wave][l15][s * 16 + quad * 4] = tp;
        }
        asm volatile("s_waitcnt lgkmcnt(0)" ::: "memory");  // wave-local order
        for (int kc = 0; kc < 4; ++kc) {
            f16x8 Pc = *(const f16x8*)&pb[wave][l15][kc * 32 + quad * 8];
            f16x8 Va = *(const f16x8*)(Vbase + (size_t)l15 * N_ + i0 + kc * 32 + quad * 8);
            f16x8 Vc = *(const f16x8*)(Vbase + (size_t)(16 + l15) * N_ + i0 + kc * 32 + quad * 8);
            O0 = __builtin_amdgcn_mfma_f32_16x16x32_f16(Va, Pc, O0, 0, 0, 0);
            O1 = __builtin_amdgcn_mfma_f32_16x16x32_f16(Vc, Pc, O1, 0, 0, 0);
        }
    }

    // finish per-split l (sum over quads), publish (m, l)
    lsum += __shfl_xor(lsum, 16);
    lsum += __shfl_xor(lsum, 32);
    if (quad == 0) { mls[wave][0][l15] = mrow; mls[wave][1][l15] = lsum; }
    __syncthreads();

    // log-sum-exp combine weights (redundant per quad, all in regs)
    float M = -1e30f, ms[4], ls[4];
    for (int s = 0; s < 4; ++s) {
        ms[s] = mls[s][0][l15]; ls[s] = mls[s][1][l15];
        M = fmaxf(M, ms[s]);
    }
    float L = 0.f;
    for (int s = 0; s < 4; ++s) L += ls[s] * exp2f(ms[s] - M);
    const float w = exp2f(mrow - M) / L;

    *(f32x4*)&osum[wave][l15][quad * 4]      = O0 * w;
    *(f32x4*)&osum[wave][l15][16 + quad * 4] = O1 * w;
    __syncthreads();

    // final cross-split sum; coalesced f16x2 stores to Ob[n][e]
    const int j  = threadIdx.x >> 4;
    const int e2 = (threadIdx.x & 15) * 2;
    float a0 = 0.f, a1 = 0.f;
    for (int s = 0; s < 4; ++s) {
        f32x2 v = *(const f32x2*)&osum[s][j][e2];
        a0 += v[0]; a1 += v[1];
    }
    f16x2 o2 = {(_Float16)a0, (_Float16)a1};
    *(f16x2*)(Ob + (size_t)(b * N_ + j0 + j) * E_ + e2) = o2;
}

// ---------------------------------------------------------------------------
// Kernel 3: output projection + bias + residual, c-split (1024 blocks, 4/CU).
// ---------------------------------------------------------------------------
__global__ __launch_bounds__(256) void out_kernel(
    const _Float16* __restrict__ Ob, const float* __restrict__ Wo,
    const float* __restrict__ bo, const float* __restrict__ x,
    float* __restrict__ out)
{
    const int bi  = blockIdx.x;            // 0..1023
    const int b   = bi >> 8;
    const int rem = bi & 255;
    const int n0  = (rem >> 2) << 6;       // n tile of 64
    const int cq  = rem & 3;               // c quarter (64 channels)
    const int t = threadIdx.x, lane = t & 63, wave = t >> 6;
    const int l15 = lane & 15, quad = lane >> 4;

    __shared__ _Float16 Wl[64][40];        // [c_local][e]
    for (int i4 = t; i4 < (64 * E_) / 4; i4 += 256) {
        int c = (i4 * 4) >> 5, e = (i4 * 4) & 31;
        float4 wv = *(const float4*)(Wo + (size_t)(cq * 64 + c) * E_ + e);
        f16x4 tp = {(_Float16)wv.x, (_Float16)wv.y, (_Float16)wv.z, (_Float16)wv.w};
        *(f16x4*)&Wl[c][e] = tp;
    }
    __syncthreads();

    const int nloc = wave * 16 + l15;
    f16x8 Bf = *(const f16x8*)(Ob + (size_t)(b * N_ + n0 + nloc) * E_ + quad * 8);

    float* out_y = out;
    float* out_o = out + (size_t)B_ * C_ * N_;

    for (int tt = 0; tt < 4; ++tt) {
        f16x8 Af = *(const f16x8*)&Wl[tt * 16 + l15][quad * 8];
        f32x4 z = {0, 0, 0, 0};
        f32x4 acc = __builtin_amdgcn_mfma_f32_16x16x32_f16(Af, Bf, z, 0, 0, 0);
        for (int r = 0; r < 4; ++r) {
            const int c = cq * 64 + tt * 16 + quad * 4 + r;
            size_t idx = (size_t)(b * C_ + c) * N_ + n0 + nloc;
            float ov = acc[r] + bo[c];
            out_o[idx] = ov;
            out_y[idx] = 0.5f * ov + x[idx];
        }
    }
    if (bi == 0 && t == 0)
        out[(size_t)2 * B_ * C_ * N_] = 0.5f;   // gamma (non-learned)
}

// ---------------------------------------------------------------------------
extern "C" void kernel_launch(void* const* d_in, const int* in_sizes, int n_in,
                              void* d_out, int out_size, void* d_ws, size_t ws_size,
                              hipStream_t stream)
{
    const float* x  = (const float*)d_in[0];
    const float* Wk = (const float*)d_in[1];
    const float* bk = (const float*)d_in[2];
    const float* Wq = (const float*)d_in[3];
    const float* bq = (const float*)d_in[4];
    const float* Wv = (const float*)d_in[5];
    const float* bv = (const float*)d_in[6];
    const float* Wo = (const float*)d_in[7];
    const float* bo = (const float*)d_in[8];
    float* out = (float*)d_out;

    char* ws = (char*)d_ws;
    _Float16* Qb = (_Float16*)(ws);                   // 1 MB [B][N][E]
    _Float16* Kb = (_Float16*)(ws + (1u << 20));      // 1 MB [B][N][E]
    _Float16* Vb = (_Float16*)(ws + (2u << 20));      // 1 MB [B][E][N]
    _Float16* Ob = (_Float16*)(ws + (3u << 20));      // 1 MB [B][N][E]

    proj_kernel<<<dim3(3 * B_ * (N_ / 64)), dim3(256), 0, stream>>>(
        x, Wk, bk, Wq, bq, Wv, bv, Qb, Kb, Vb);
    attn_kernel<<<dim3(B_ * (N_ / 16)), dim3(256), 0, stream>>>(
        Qb, Kb, Vb, Ob);
    out_kernel <<<dim3(4 * B_ * (N_ / 64)), dim3(256), 0, stream>>>(
        Ob, Wo, bo, x, out);
}